// Round 1
// baseline (115.121 us; speedup 1.0000x reference)
//
#include <hip/hip_runtime.h>
#include <hip/hip_bf16.h>
#include <math.h>

#define NH 8
#define C_ 512
#define C3 1536
#define NTOK 16384   // b*t*h*w = 2*8*32*32

typedef __attribute__((ext_vector_type(8))) short short8;
typedef __attribute__((ext_vector_type(4))) float f32x4;
typedef __attribute__((address_space(3))) void* lds_ptr_t;
typedef const __attribute__((address_space(1))) void* gbl_ptr_t;

static __device__ __forceinline__ ushort f2bf(float f) {
  __hip_bfloat16 h = __float2bfloat16(f);
  return *reinterpret_cast<ushort*>(&h);
}
static __device__ __forceinline__ float bf2f(ushort u) {
  uint t = ((uint)u) << 16;
  float f;
  __builtin_memcpy(&f, &t, 4);
  return f;
}

#define GLD16(src, dst) \
  __builtin_amdgcn_global_load_lds((gbl_ptr_t)(const void*)(src), (lds_ptr_t)(dst), 16, 0, 0)

// ---------------------------------------------------------------------------
// K0: fused fp32 -> bf16 cast for x, w_in, w_out (one launch, exact ranges)
// ---------------------------------------------------------------------------
__global__ __launch_bounds__(256) void cast3_kernel(
    const float* __restrict__ x, const float* __restrict__ wi,
    const float* __restrict__ wo, ushort* __restrict__ xb,
    ushort* __restrict__ wib, ushort* __restrict__ wob) {
  const int blk = blockIdx.x;
  const float* src;
  ushort* dst;
  int i;
  if (blk < 4096)      { src = x;  dst = xb;  i = blk * 256 + threadIdx.x; }
  else if (blk < 4480) { src = wi; dst = wib; i = (blk - 4096) * 256 + threadIdx.x; }
  else                 { src = wo; dst = wob; i = (blk - 4480) * 256 + threadIdx.x; }
  const float4* p = (const float4*)src + (size_t)i * 2;
  float4 v0 = p[0], v1 = p[1];
  union { ushort u[8]; uint4 v; } r;
  r.u[0] = f2bf(v0.x); r.u[1] = f2bf(v0.y); r.u[2] = f2bf(v0.z); r.u[3] = f2bf(v0.w);
  r.u[4] = f2bf(v1.x); r.u[5] = f2bf(v1.y); r.u[6] = f2bf(v1.z); r.u[7] = f2bf(v1.w);
  *(uint4*)(dst + (size_t)i * 8) = r.v;
}

// ---------------------------------------------------------------------------
// K1a: NEW 256x256x64 8-phase bf16 NT GEMM (T1+T2+T3+T4+T5), bf16 out.
// 512 threads = 8 waves (2M x 4N); per-wave 128x64 out; 16 MFMA/phase.
// LDS 128 KB: 2 buffers x (A[256][64] + B[256][64]).
// Swizzle: 16B chunk slot = g ^ (row&7) (source-side pre-swizzle, linear
// global_load_lds dest, same XOR on ds_read) -> 2-way max on reads.
// Counted vmcnt: stage order per K-tile {A0,A2 | B0,B1 | B2,B3 | A1,A3};
// boundary wait vmcnt(2) (A1,A3 in flight), mid-tile wait vmcnt(4).
// ---------------------------------------------------------------------------
__global__ __launch_bounds__(512, 2) void gemm256_8ph_bf16(
    const ushort* __restrict__ A, const ushort* __restrict__ B,
    ushort* __restrict__ C, int N, int K, int GX) {
  __shared__ ushort smem[65536];   // 128 KB
  const int tid  = threadIdx.x;
  const int wave = tid >> 6;
  const int lane = tid & 63;
  const int lm = lane & 15, g4 = lane >> 4;
  const int wm = wave >> 2, wn = wave & 3;
  const int nwg = gridDim.x;
  const int wg = (blockIdx.x & 7) * (nwg >> 3) + (blockIdx.x >> 3);
  const int bm = (wg / GX) * 256;
  const int bn = (wg % GX) * 256;

  // per-thread staging geometry: 1 load per 64-row stripe; row-in-stripe,
  // chunk g; source chunk pre-swizzled so LDS[row][g] = glb[row][g^(row&7)].
  const int trow = tid >> 3;                       // 0..63
  const int slot8 = ((tid & 7) ^ (trow & 7)) * 8;  // pre-swizzled k-chunk (ushorts)
  const ushort* Arow = A + (size_t)(bm + trow) * K + slot8;
  const ushort* Brow = B + (size_t)(bn + trow) * K + slot8;
  const size_t sstr = (size_t)64 * K;              // stripe-to-stripe source step
  ushort* ldsT = smem + tid * 8;                   // linear dest base (buffer 0)

  const int nt = K >> 6;

  f32x4 acc[8][4];
#pragma unroll
  for (int m = 0; m < 8; ++m)
#pragma unroll
    for (int n = 0; n < 4; ++n) acc[m][n] = (f32x4){0.f, 0.f, 0.f, 0.f};

  // ---- prologue: stage K-tile 0 into buf0, same issue order as steady state
  GLD16(Arow + 0 * sstr, ldsT + 0);            // A0
  GLD16(Arow + 2 * sstr, ldsT + 8192);         // A2
  GLD16(Brow + 0 * sstr, ldsT + 16384);        // B0
  GLD16(Brow + 1 * sstr, ldsT + 20480);        // B1
  GLD16(Brow + 2 * sstr, ldsT + 24576);        // B2
  GLD16(Brow + 3 * sstr, ldsT + 28672);        // B3
  GLD16(Arow + 1 * sstr, ldsT + 4096);         // A1
  GLD16(Arow + 3 * sstr, ldsT + 12288);        // A3
  asm volatile("s_waitcnt vmcnt(2)" ::: "memory");   // A0,A2,B* landed
  __builtin_amdgcn_s_barrier();
  asm volatile("" ::: "memory");

  int cur = 0;
  for (int t = 0; t < nt; ++t) {
    const ushort* As = smem + cur * 32768;
    const ushort* Bs = As + 16384;
    ushort* Ln = smem + (cur ^ 1) * 32768 + tid * 8;
    const ushort* An = Arow + (size_t)(t + 1) * 64;
    const ushort* Bn = Brow + (size_t)(t + 1) * 64;
    const bool st = (t + 1 < nt);
    short8 a[4][2], bb[2][2];
#pragma unroll
    for (int p = 0; p < 4; ++p) {
      const int qm = p >> 1, qn = p & 1;
      // ds-reads: A quadrant on even phases (reused by the odd phase), B every phase
      if ((p & 1) == 0) {
#pragma unroll
        for (int mf = 0; mf < 4; ++mf)
#pragma unroll
          for (int kk = 0; kk < 2; ++kk) {
            const int row = wm * 128 + qm * 64 + mf * 16 + lm;
            a[mf][kk] = *(const short8*)&As[row * 64 + (((kk * 4 + g4) ^ (lm & 7)) * 8)];
          }
      }
#pragma unroll
      for (int nf = 0; nf < 2; ++nf)
#pragma unroll
        for (int kk = 0; kk < 2; ++kk) {
          const int row = wn * 64 + qn * 32 + nf * 16 + lm;
          bb[nf][kk] = *(const short8*)&Bs[row * 64 + (((kk * 4 + g4) ^ (lm & 7)) * 8)];
        }
      // stage next K-tile, 2 stripes per phase (latency-ranked order)
      if (st) {
        if (p == 0) { GLD16(An + 0 * sstr, Ln + 0);     GLD16(An + 2 * sstr, Ln + 8192);  }
        if (p == 1) { GLD16(Bn + 0 * sstr, Ln + 16384); GLD16(Bn + 1 * sstr, Ln + 20480); }
        if (p == 2) { GLD16(Bn + 2 * sstr, Ln + 24576); GLD16(Bn + 3 * sstr, Ln + 28672); }
        if (p == 3) { GLD16(An + 1 * sstr, Ln + 4096);  GLD16(An + 3 * sstr, Ln + 12288); }
      }
      __builtin_amdgcn_s_barrier();
      asm volatile("s_waitcnt lgkmcnt(0)" ::: "memory");
      __builtin_amdgcn_s_setprio(1);
#pragma unroll
      for (int mf = 0; mf < 4; ++mf)
#pragma unroll
        for (int nf = 0; nf < 2; ++nf)
#pragma unroll
          for (int kk = 0; kk < 2; ++kk)
            acc[qm * 4 + mf][qn * 2 + nf] = __builtin_amdgcn_mfma_f32_16x16x32_bf16(
                a[mf][kk], bb[nf][kk], acc[qm * 4 + mf][qn * 2 + nf], 0, 0, 0);
      __builtin_amdgcn_s_setprio(0);
      if (p == 1) {   // before phases 2-3 read A1/A3 of the CURRENT tile
        if (st) asm volatile("s_waitcnt vmcnt(4)" ::: "memory");
        else    asm volatile("s_waitcnt vmcnt(0)" ::: "memory");
      }
      if (p == 3 && st)  // tile boundary: allow next tile's A1,A3 in flight
        asm volatile("s_waitcnt vmcnt(2)" ::: "memory");
      __builtin_amdgcn_s_barrier();
      asm volatile("" ::: "memory");
    }
    cur ^= 1;
  }

  // ---- epilogue: stage full 256x256 bf16 C-tile in LDS, coalesced stores
  __syncthreads();
  ushort* Cs = smem;
#pragma unroll
  for (int mf = 0; mf < 8; ++mf)
#pragma unroll
    for (int nf = 0; nf < 4; ++nf)
#pragma unroll
      for (int r = 0; r < 4; ++r)
        Cs[(wm * 128 + mf * 16 + g4 * 4 + r) * 256 + wn * 64 + nf * 16 + lm] =
            f2bf(acc[mf][nf][r]);
  __syncthreads();
#pragma unroll
  for (int i = 0; i < 16; ++i) {
    const int idx = i * 512 + tid;
    const int row = idx >> 5, ch = idx & 31;
    uint4 v = *(const uint4*)&Cs[row * 256 + ch * 8];
    *(uint4*)(C + (size_t)(bm + row) * N + bn + ch * 8) = v;
  }
}

// ---------------------------------------------------------------------------
// K1b: old bf16 NT GEMM via MFMA (kept for gemm2, fp32 out): 128x128x32
// prefetch double-buffer, T2 source swizzle, T1 XCD swizzle, LDS epilogue.
// ---------------------------------------------------------------------------
#define TBM 128
#define TBN 128
#define TBK 32
#define TILE_U ((TBM + TBN) * TBK)

static __device__ __forceinline__ void stage_tile(
    const ushort* __restrict__ A, const ushort* __restrict__ B,
    ushort* As, ushort* Bs, int bm, int bn, int K, int k0, int tid) {
#pragma unroll
  for (int it = 0; it < 2; ++it) {
    int c = it * 256 + tid;
    int row = c >> 2;
    int sk = ((c & 3) ^ ((row >> 1) & 3)) * 8;
    __builtin_amdgcn_global_load_lds(
        (gbl_ptr_t)(const void*)(A + (size_t)(bm + row) * K + k0 + sk),
        (lds_ptr_t)(As + (size_t)c * 8), 16, 0, 0);
    __builtin_amdgcn_global_load_lds(
        (gbl_ptr_t)(const void*)(B + (size_t)(bn + row) * K + k0 + sk),
        (lds_ptr_t)(Bs + (size_t)c * 8), 16, 0, 0);
  }
}

template <bool BF16OUT>
__global__ __launch_bounds__(256) void gemm_bt_bf16(
    const ushort* __restrict__ A, const ushort* __restrict__ B,
    void* __restrict__ Cv, int N, int K, int GX) {
  __shared__ ushort smem[2 * TILE_U];
  const int tid  = threadIdx.x;
  const int wave = tid >> 6;
  const int lane = tid & 63;
  const int nwg = gridDim.x;
  const int wg = (blockIdx.x & 7) * (nwg >> 3) + (blockIdx.x >> 3);
  const int bm = (wg / GX) * TBM;
  const int bn = (wg % GX) * TBN;
  const int wr = (wave >> 1) * 64;
  const int wc = (wave & 1) * 64;
  const int lm = lane & 15;
  const int g4 = lane >> 4;

  f32x4 acc[4][4];
#pragma unroll
  for (int m = 0; m < 4; ++m)
#pragma unroll
    for (int n = 0; n < 4; ++n) acc[m][n] = (f32x4){0.f, 0.f, 0.f, 0.f};

  const int ko = (g4 ^ ((lm >> 1) & 3)) * 8;

  const int nt = K / TBK;
  stage_tile(A, B, smem, smem + TBM * TBK, bm, bn, K, 0, tid);
  __syncthreads();

  int cur = 0;
  for (int t = 0; t < nt; ++t) {
    if (t + 1 < nt) {
      ushort* Asn = smem + (cur ^ 1) * TILE_U;
      stage_tile(A, B, Asn, Asn + TBM * TBK, bm, bn, K, (t + 1) * TBK, tid);
    }
    const ushort* As = smem + cur * TILE_U;
    const ushort* Bs = As + TBM * TBK;
    short8 av[4], bv[4];
#pragma unroll
    for (int m = 0; m < 4; ++m)
      av[m] = *(const short8*)&As[(wr + m * 16 + lm) * TBK + ko];
#pragma unroll
    for (int n = 0; n < 4; ++n)
      bv[n] = *(const short8*)&Bs[(wc + n * 16 + lm) * TBK + ko];
#pragma unroll
    for (int m = 0; m < 4; ++m)
#pragma unroll
      for (int n = 0; n < 4; ++n)
        acc[m][n] = __builtin_amdgcn_mfma_f32_16x16x32_bf16(av[m], bv[n], acc[m][n], 0, 0, 0);
    __syncthreads();
    cur ^= 1;
  }

  const int cr = g4 * 4;
  const int cc = lm;

  if (BF16OUT) {
    ushort* Cs = smem;
    ushort* C = (ushort*)Cv;
#pragma unroll
    for (int h = 0; h < 2; ++h) {
      __syncthreads();
      if ((wave >> 1) == h) {
#pragma unroll
        for (int m = 0; m < 4; ++m)
#pragma unroll
          for (int n = 0; n < 4; ++n)
#pragma unroll
            for (int r = 0; r < 4; ++r)
              Cs[(m * 16 + cr + r) * 128 + wc + n * 16 + cc] = f2bf(acc[m][n][r]);
      }
      __syncthreads();
#pragma unroll
      for (int i = 0; i < 4; ++i) {
        int idx = i * 256 + tid;
        int row = idx >> 4, ch = idx & 15;
        uint4 v = *(const uint4*)&Cs[row * 128 + ch * 8];
        *(uint4*)(C + (size_t)(bm + h * 64 + row) * N + bn + ch * 8) = v;
      }
    }
  } else {
    float* Csf = (float*)smem;
    float* C = (float*)Cv;
#pragma unroll
    for (int s = 0; s < 4; ++s) {
      __syncthreads();
      if ((wave >> 1) == (s >> 1)) {
#pragma unroll
        for (int mi = 0; mi < 2; ++mi)
#pragma unroll
          for (int n = 0; n < 4; ++n)
#pragma unroll
            for (int r = 0; r < 4; ++r) {
              int m = (s & 1) * 2 + mi;
              Csf[(mi * 16 + cr + r) * 128 + wc + n * 16 + cc] = acc[m][n][r];
            }
      }
      __syncthreads();
#pragma unroll
      for (int i = 0; i < 4; ++i) {
        int idx = i * 256 + tid;
        int row = idx >> 5, ch = idx & 31;
        float4 v = *(const float4*)&Csf[row * 128 + ch * 4];
        *(float4*)(C + (size_t)(bm + s * 32 + row) * N + bn + ch * 4) = v;
      }
    }
  }
}

// ---------------------------------------------------------------------------
// K2: fused RMSNorm + rotary (unchanged)
// ---------------------------------------------------------------------------
__global__ __launch_bounds__(256) void norm_rope_kernel(
    ushort* __restrict__ qkv, const float* __restrict__ freqs,
    const float* __restrict__ qg, const float* __restrict__ kg) {
  const int task = blockIdx.x * 4 + (threadIdx.x >> 6);
  const int L = threadIdx.x & 63;
  const int n = task & 7;
  const int m = task >> 3;
  const int w = m & 31, h = (m >> 5) & 31, t = (m >> 10) & 7;
  const int dp = L & 31;

  ushort* base = qkv + (size_t)m * C3 + n * 192;
  uint val = *(uint*)(base + 2 * L);
  float x0 = bf2f((ushort)(val & 0xffffu));
  float x1 = bf2f((ushort)(val >> 16));

  float ss = x0 * x0 + x1 * x1;
#pragma unroll
  for (int off = 16; off >= 1; off >>= 1) ss += __shfl_xor(ss, off, 32);
  const float r = rsqrtf(ss * (1.f / 64.f) + 1e-6f);
  const float* gp = (L < 32) ? qg : kg;
  const float xe = x0 * r * gp[2 * dp];
  const float xo = x1 * r * gp[2 * dp + 1];

  const float f = freqs[(((t * 32 + h) * 32 + w) * 32) + dp];
  const float c = cosf(f), s = sinf(f);
  ushort o0 = f2bf(xe * c - xo * s);
  ushort o1 = f2bf(xe * s + xo * c);
  *(uint*)(base + 2 * L) = (uint)o0 | ((uint)o1 << 16);
}

// ---------------------------------------------------------------------------
// K3: MFMA neighborhood attention (unchanged)
// ---------------------------------------------------------------------------
__global__ __launch_bounds__(256) void attn_kernel(
    const ushort* __restrict__ qkv, ushort* __restrict__ outb) {
  __shared__ ushort lds[24576];          // 48 KB
  ushort* K_s  = lds;                    // [192 k][64 d], chunk swz c^(kr&7)
  ushort* Vt_s = lds + 12288;            // [64 d][192 k], chunk low3 ^ (d&7)^((d>>3)&7)
  ushort* P_s  = lds;                    // [64 q][192 k], chunk low3 ^ (q&7)
  ushort* O_s  = lds + 12288;            // [64 q][68 d-stride]

  const int tid = threadIdx.x;
  const int wave = tid >> 6;
  const int lane = tid & 63;
  const int lin = blockIdx.x;
  const int bid = (lin & 7) * 256 + (lin >> 3);   // XCD-chunked (2048 % 8 == 0)
  // bid = ((b*8 + n)*16 + th)*8 + tw
  const int tw = bid & 7, th = (bid >> 3) & 15, n = (bid >> 7) & 7, b = bid >> 10;
  const int hb = th * 2, wb = tw * 4;
  const int hb0 = max(hb - 1, 0), wb0 = max(wb - 1, 0);
  const int lm = lane & 15, g4 = lane >> 4;

  // ---- V: reg-stage 6 chunks/thread (plain) ----
  float4 vreg[6];
#pragma unroll
  for (int it = 0; it < 6; ++it) {
    int c = it * 256 + tid;
    int kr = c >> 3, gv = c & 7;
    int sc = kr >> 3, t = kr & 7;
    int kh = sc / 6, kw = sc - kh * 6;
    int hh = min(hb0 + kh, 31), ww = min(wb0 + kw, 31);
    size_t m = (((size_t)(b * 8 + t) * 32 + hh) * 32 + ww);
    vreg[it] = *(const float4*)(qkv + m * C3 + n * 192 + 128 + gv * 8);
  }

  // ---- K: global_load_lds, source-side XOR swz (1536 chunks) ----
#pragma unroll
  for (int it = 0; it < 6; ++it) {
    int c = it * 256 + tid;
    int kr = c >> 3, g = (c & 7) ^ (kr & 7);
    int sc = kr >> 3, t = kr & 7;
    int kh = sc / 6, kw = sc - kh * 6;
    int hh = min(hb0 + kh, 31), ww = min(wb0 + kw, 31);
    size_t m = (((size_t)(b * 8 + t) * 32 + hh) * 32 + ww);
    const ushort* srcK = qkv + m * C3 + n * 192 + 64 + g * 8;
    ushort* dstK = K_s + (size_t)(it * 256 + wave * 64) * 8;
    __builtin_amdgcn_global_load_lds((gbl_ptr_t)(const void*)srcK, (lds_ptr_t)dstK, 16, 0, 0);
  }

  // ---- Q: wave's 16-q fragment direct from global ----
  short8 bq[2];
  {
    int q = wave * 16 + lm;
    int tq = q >> 3, p = q & 7;
    size_t mq = (((size_t)(b * 8 + tq) * 32 + (hb + (p >> 2))) * 32 + (wb + (p & 3)));
    const ushort* qp = qkv + mq * C3 + n * 192;
#pragma unroll
    for (int kk = 0; kk < 2; ++kk)
      bq[kk] = *(const short8*)(qp + (kk * 4 + g4) * 8);
  }

  __syncthreads();  // bar1: K staged (drains V/Q loads too)

  // ---- Vt transposed scatter-write (overlaps St on LDS pipe) ----
#pragma unroll
  for (int it = 0; it < 6; ++it) {
    int c = it * 256 + tid;
    int kr = c >> 3, gv = c & 7;
    int ck = kr >> 3, kin = kr & 7;
    union { float4 f; ushort u[8]; } vv;
    vv.f = vreg[it];
#pragma unroll
    for (int j = 0; j < 8; ++j) {
      int d = gv * 8 + j;
      int cks = ck ^ ((j ^ gv) & 7);       // group-preserving low-3 XOR
      Vt_s[d * 192 + cks * 8 + kin] = vv.u[j];
    }
  }

  // ---- St = K·Q^T : wave computes ONLY its 16 q (no redundancy) ----
  f32x4 st[12];
#pragma unroll
  for (int kf = 0; kf < 12; ++kf) st[kf] = (f32x4){0.f, 0.f, 0.f, 0.f};
#pragma unroll
  for (int kk = 0; kk < 2; ++kk)
#pragma unroll
    for (int kf = 0; kf < 12; ++kf) {
      int kr = kf * 16 + lm;
      short8 a = *(const short8*)&K_s[kr * 64 + (((kk * 4 + g4) ^ (kr & 7)) * 8)];
      st[kf] = __builtin_amdgcn_mfma_f32_16x16x32_bf16(a, bq[kk], st[kf], 0, 0, 0);
    }

  // ---- mask + softmax (lane: q-col = wave*16+lm; k = kf*16 + g4*4 + r) ----
  const int p = lm & 7;                   // (wave*16+lm)&7 == lm&7
  const int qh = hb + (p >> 2), qw = wb + (p & 3);
  const int loh = min(max(qh - 1, 0), 29), low = min(max(qw - 1, 0), 29);
  uint mk = 0;
#pragma unroll
  for (int kf = 0; kf < 12; ++kf) {
    int sc = kf * 2 + (g4 >> 1);
    int kh = sc / 6, kw = sc - kh * 6;
    int khg = hb0 + kh, kwg = wb0 + kw;   // nominal (unclamped) position
    bool ok = (khg >= loh) && (khg <= loh + 2) && (kwg >= low) && (kwg <= low + 2);
    mk |= (uint)ok << kf;
  }
  const float scale = 0.125f;
#pragma unroll
  for (int kf = 0; kf < 12; ++kf) {
    bool ok = (mk >> kf) & 1;
#pragma unroll
    for (int r = 0; r < 4; ++r)
      st[kf][r] = ok ? st[kf][r] * scale : -1e30f;
  }
  float mx = -1e30f;
#pragma unroll
  for (int kf = 0; kf < 12; ++kf)
#pragma unroll
    for (int r = 0; r < 4; ++r) mx = fmaxf(mx, st[kf][r]);
  mx = fmaxf(mx, __shfl_xor(mx, 16));
  mx = fmaxf(mx, __shfl_xor(mx, 32));
  float s = 0.f;
#pragma unroll
  for (int kf = 0; kf < 12; ++kf)
#pragma unroll
    for (int r = 0; r < 4; ++r) {
      float e = __expf(st[kf][r] - mx);
      st[kf][r] = e;
      s += e;
    }
  s += __shfl_xor(s, 16);
  s += __shfl_xor(s, 32);
  const float inv = 1.f / s;
  __syncthreads();  // bar2: K reads done (P may overwrite), Vt writes visible

  // ---- P write: wave-disjoint rows q = wave*16+lm; compile-time st idx ----
  {
    const int q = wave * 16 + lm;
    ushort* Prow = P_s + q * 192 + (g4 & 1) * 4;
#pragma unroll
    for (int kf = 0; kf < 12; ++kf) {
      uint lo = (uint)f2bf(st[kf][0] * inv) | ((uint)f2bf(st[kf][1] * inv) << 16);
      uint hi = (uint)f2bf(st[kf][2] * inv) | ((uint)f2bf(st[kf][3] * inv) << 16);
      int ck = kf * 2 + (g4 >> 1);
      int cks = ck ^ (lm & 7);            // group-preserving (q&7 == lm&7)
      uint2 val; val.x = lo; val.y = hi;
      *(uint2*)(Prow + cks * 8) = val;
    }
  }
  __syncthreads();  // bar3: P ready

  // ---- PV: wave owns d-block wave*16; out[q][d] for all 4 q-frags ----
  f32x4 ao0 = (f32x4){0.f, 0.f, 0.f, 0.f};
  f32x4 ao1 = (f32x4){0.f, 0.f, 0.f, 0.f};
  f32x4 ao2 = (f32x4){0.f, 0.f, 0.f, 0.f};
  f32x4 ao3 = (f32x4){0.f, 0.f, 0.f, 0.f};
  const int drow = wave * 16 + lm;
  const int dsw = (lm & 7) ^ ((wave * 2 + (lm >> 3)) & 7);
#pragma unroll
  for (int kk = 0; kk < 6; ++kk) {
    int ch = kk * 4 + g4;
    short8 bv = *(const short8*)&Vt_s[drow * 192 + ((ch ^ dsw) * 8)];
    int pch = (ch ^ (lm & 7)) * 8;
    short8 av0 = *(const short8*)&P_s[(0 * 16 + lm) * 192 + pch];
    short8 av1 = *(const short8*)&P_s[(1 * 16 + lm) * 192 + pch];
    short8 av2 = *(const short8*)&P_s[(2 * 16 + lm) * 192 + pch];
    short8 av3 = *(const short8*)&P_s[(3 * 16 + lm) * 192 + pch];
    ao0 = __builtin_amdgcn_mfma_f32_16x16x32_bf16(av0, bv, ao0, 0, 0, 0);
    ao1 = __builtin_amdgcn_mfma_f32_16x16x32_bf16(av1, bv, ao1, 0, 0, 0);
    ao2 = __builtin_amdgcn_mfma_f32_16x16x32_bf16(av2, bv, ao2, 0, 0, 0);
    ao3 = __builtin_amdgcn_mfma_f32_16x16x32_bf16(av3, bv, ao3, 0, 0, 0);
  }
  __syncthreads();  // bar4: PV's Vt/P reads done; O may overwrite Vt region

  // ---- epilogue: O via LDS (stride 68), coalesced bf16 store ----
#pragma unroll
  for (int r = 0; r < 4; ++r) {
    O_s[(0 * 16 + g4 * 4 + r) * 68 + (wave * 16 + lm)] = f2bf(ao0[r]);
    O_s[(1 * 16 + g4 * 4 + r) * 68 + (wave * 16 + lm)] = f2bf(ao1[r]);
    O_s[(2 * 16 + g4 * 4 + r) * 68 + (wave * 16 + lm)] = f2bf(ao2[r]);
    O_s[(3 * 16 + g4 * 4 + r) * 68 + (wave * 16 + lm)] = f2bf(ao3[r]);
  }
  __syncthreads();  // bar5
#pragma unroll
  for (int i = 0; i < 2; ++i) {
    int idx = i * 256 + tid;
    int q = idx >> 3, c = idx & 7;
    short8 v = *(const short8*)&O_s[q * 68 + c * 8];
    int tq = q >> 3, pp = q & 7;
    size_t m = (((size_t)(b * 8 + tq) * 32 + (hb + (pp >> 2))) * 32 + (wb + (pp & 3)));
    *(short8*)(outb + m * (size_t)C_ + n * 64 + c * 8) = v;
  }
}

// ---------------------------------------------------------------------------
extern "C" void kernel_launch(void* const* d_in, const int* in_sizes, int n_in,
                              void* d_out, int out_size, void* d_ws, size_t ws_size,
                              hipStream_t stream) {
  const float* x     = (const float*)d_in[0];
  const float* freqs = (const float*)d_in[1];
  const float* w_in  = (const float*)d_in[2];
  const float* w_out = (const float*)d_in[3];
  const float* qg    = (const float*)d_in[4];
  const float* kg    = (const float*)d_in[5];
  float* out = (float*)d_out;

  char* ws = (char*)d_ws;
  ushort* qkv   = (ushort*)ws;                                    // 50.3 MB bf16
  ushort* xb    = (ushort*)(ws + (size_t)NTOK * C3 * 2);          // 16.8 MB
  ushort* wib   = xb + (size_t)NTOK * C_;                         // 1.5 MB
  ushort* wob   = wib + (size_t)C3 * C_;                          // 0.5 MB
  ushort* attnb = wob + (size_t)C_ * C_;                          // 16.8 MB

  // 0) fused casts
  cast3_kernel<<<4608, 256, 0, stream>>>(x, w_in, w_out, xb, wib, wob);

  // 1) qkv = x @ w_in^T (bf16 out). NEW 8-phase 256x256 kernel.
  //    grid 384 = 64 bm x 6 bn, XCD-chunked (384 % 8 == 0).
  gemm256_8ph_bf16<<<384, 512, 0, stream>>>(xb, wib, qkv, C3, C_, 6);
  // 2) rmsnorm + rope in place on bf16
  norm_rope_kernel<<<(NTOK * NH) / 4, 256, 0, stream>>>(qkv, freqs, qg, kg);
  // 3) MFMA neighborhood attention -> attnb. grid 2048 = 2b x 8n x 16th x 8tw.
  attn_kernel<<<2048, 256, 0, stream>>>(qkv, attnb);
  // 4) out = attn @ w_out^T (fp32 out). grid 512 = 128 bm x 4 bn.
  gemm_bt_bf16<false><<<512, 256, 0, stream>>>(attnb, wob, out, C_, C_, 4);
}